// Round 1
// baseline (1551.832 us; speedup 1.0000x reference)
//
#include <hip/hip_runtime.h>
#include <cstdint>

// TemporalLinkLayer: out[b] = Wfc · [relu([featu,dtu]@W1.T+b1), relu([featv,dtv]@W1.T+b1)] + bfc
// Strategy: bf16 MFMA 16x16x32 GEMM, K=128 (dt column peeled into epilogue),
// waves split N (W1 fragments in registers), fc fused into epilogue.

#define D 128
#define ROWS_PER_CHUNK 64
#define CHUNKS_PER_BLOCK 4
#define ROWS_PER_BLOCK 256
#define LDS_STRIDE 136   // bf16 elements; +8 pad -> 2-way bank aliasing (free)

typedef __attribute__((ext_vector_type(8))) __bf16 bf16x8;
typedef __attribute__((ext_vector_type(8))) unsigned short ushort8;
typedef __attribute__((ext_vector_type(4))) float floatx4;

union Frag8 { ushort8 u; bf16x8 b; };

__device__ __forceinline__ unsigned short f2bf(float f) {
    union { float f; uint32_t u; } v; v.f = f;
    uint32_t u = v.u;
    return (unsigned short)((u + 0x7fffu + ((u >> 16) & 1u)) >> 16);  // RNE
}

__global__ __launch_bounds__(256, 2)
void tll_kernel(const float* __restrict__ src_feat,
                const float* __restrict__ dst_feat,
                const float* __restrict__ timestamp,
                const int*   __restrict__ src_eids,
                const int*   __restrict__ dst_eids,
                const float* __restrict__ tarr,
                const float* __restrict__ W1,
                const float* __restrict__ b1,
                const float* __restrict__ Wfc,
                const float* __restrict__ bfc,
                float* __restrict__ out)
{
    __shared__ __align__(16) unsigned short bufU[ROWS_PER_CHUNK * LDS_STRIDE];
    __shared__ __align__(16) unsigned short bufV[ROWS_PER_CHUNK * LDS_STRIDE];
    __shared__ float lds_dtu[ROWS_PER_CHUNK];
    __shared__ float lds_dtv[ROWS_PER_CHUNK];
    __shared__ float lds_out[ROWS_PER_CHUNK];

    const int tid  = threadIdx.x;
    const int lane = tid & 63;
    const int wave = tid >> 6;    // 0..3, owns N-tiles {2w, 2w+1}
    const int col  = lane & 15;   // MFMA: A-row m / C-col n / B-col n
    const int quad = lane >> 4;   // MFMA: k-slice for A/B, row-group for C

    // ---- per-block constants: W1 B-fragments (registers), epilogue scalars ----
    // B[k][n] = W1[n][k]; lane holds B[ks*32 + quad*8 + j][tile*16 + col], j=0..7
    Frag8 bfrag[2][4];
    float b1v[2], wfu[2], wfv[2], w1l[2];
    #pragma unroll
    for (int tt = 0; tt < 2; ++tt) {
        const int n = (wave * 2 + tt) * 16 + col;
        const float* wrow = W1 + n * (D + 1);
        #pragma unroll
        for (int ks = 0; ks < 4; ++ks) {
            const int k0 = ks * 32 + quad * 8;
            ushort8 u;
            #pragma unroll
            for (int j = 0; j < 8; ++j) u[j] = f2bf(wrow[k0 + j]);
            bfrag[tt][ks].u = u;
        }
        b1v[tt] = b1[n];
        wfu[tt] = Wfc[n];
        wfv[tt] = Wfc[D + n];
        w1l[tt] = wrow[D];        // dt column of W1
    }
    const float bfcv = bfc[0];

    if (tid < ROWS_PER_CHUNK) lds_out[tid] = 0.f;

    const int r = tid >> 2;   // staging: row within chunk
    const int p = tid & 3;    // staging: 4 threads per row
    const int block_base = blockIdx.x * ROWS_PER_BLOCK;

    for (int c = 0; c < CHUNKS_PER_BLOCK; ++c) {
        const int base = block_base + c * ROWS_PER_CHUNK;

        // ---- stage: gather fp32 rows -> bf16 LDS tiles ----
        {
            const int g  = base + r;
            const int eu = src_eids[g];
            const int ev = dst_eids[g];
            const float* su = src_feat + (size_t)eu * D;
            const float* sv = dst_feat + (size_t)ev * D;
            if (p == 0) {
                const float tg = tarr[g];
                lds_dtu[r] = tg - timestamp[eu];
                lds_dtv[r] = tg - timestamp[ev];
            }
            #pragma unroll
            for (int i = 0; i < 8; ++i) {
                const int e = i * 16 + p * 4;   // 4 threads cover 64B per row per iter
                const float4 fu = *(const float4*)(su + e);
                const float4 fv = *(const float4*)(sv + e);
                ushort4 wu, wv;
                wu.x = f2bf(fu.x); wu.y = f2bf(fu.y); wu.z = f2bf(fu.z); wu.w = f2bf(fu.w);
                wv.x = f2bf(fv.x); wv.y = f2bf(fv.y); wv.z = f2bf(fv.z); wv.w = f2bf(fv.w);
                *(ushort4*)(&bufU[r * LDS_STRIDE + e]) = wu;
                *(ushort4*)(&bufV[r * LDS_STRIDE + e]) = wv;
            }
        }
        __syncthreads();

        // ---- compute: per 16-row M-tile, both GEMMs + fused fc epilogue ----
        #pragma unroll
        for (int mt = 0; mt < 4; ++mt) {
            Frag8 au[4], av[4];
            const int arow = mt * 16 + col;   // A[m=lane&15][k=ks*32+quad*8+j]
            #pragma unroll
            for (int ks = 0; ks < 4; ++ks) {
                const int off = arow * LDS_STRIDE + ks * 32 + quad * 8;
                au[ks].u = *(const ushort8*)&bufU[off];
                av[ks].u = *(const ushort8*)&bufV[off];
            }
            float dtu[4], dtv[4];
            #pragma unroll
            for (int i = 0; i < 4; ++i) {
                dtu[i] = lds_dtu[mt * 16 + quad * 4 + i];
                dtv[i] = lds_dtv[mt * 16 + quad * 4 + i];
            }
            float part[4] = {0.f, 0.f, 0.f, 0.f};
            #pragma unroll
            for (int tt = 0; tt < 2; ++tt) {
                floatx4 accu = {0.f, 0.f, 0.f, 0.f};
                floatx4 accv = {0.f, 0.f, 0.f, 0.f};
                #pragma unroll
                for (int ks = 0; ks < 4; ++ks) {
                    accu = __builtin_amdgcn_mfma_f32_16x16x32_bf16(au[ks].b, bfrag[tt][ks].b, accu, 0, 0, 0);
                    accv = __builtin_amdgcn_mfma_f32_16x16x32_bf16(av[ks].b, bfrag[tt][ks].b, accv, 0, 0, 0);
                }
                // C/D: row = quad*4 + i, col n = tile*16 + (lane&15)
                #pragma unroll
                for (int i = 0; i < 4; ++i) {
                    float pu = fmaxf(fmaf(dtu[i], w1l[tt], accu[i]) + b1v[tt], 0.f);
                    float pv = fmaxf(fmaf(dtv[i], w1l[tt], accv[i]) + b1v[tt], 0.f);
                    part[i] = fmaf(pu, wfu[tt], fmaf(pv, wfv[tt], part[i]));
                }
            }
            // reduce over the 16 cols held by lanes sharing a quad
            #pragma unroll
            for (int m = 1; m <= 8; m <<= 1) {
                #pragma unroll
                for (int i = 0; i < 4; ++i)
                    part[i] += __shfl_xor(part[i], m, 64);
            }
            if (col == 0) {
                #pragma unroll
                for (int i = 0; i < 4; ++i)
                    atomicAdd(&lds_out[mt * 16 + quad * 4 + i], part[i]);
            }
        }
        __syncthreads();

        if (tid < ROWS_PER_CHUNK) {
            out[base + tid] = lds_out[tid] + bfcv;
            lds_out[tid] = 0.f;   // same thread reads then zeroes: no race
        }
        // next chunk's atomics are ordered after its stage-barrier; safe.
    }
}

extern "C" void kernel_launch(void* const* d_in, const int* in_sizes, int n_in,
                              void* d_out, int out_size, void* d_ws, size_t ws_size,
                              hipStream_t stream) {
    const float* src_feat  = (const float*)d_in[0];
    const float* dst_feat  = (const float*)d_in[1];
    const float* timestamp = (const float*)d_in[2];
    const int*   src_eids  = (const int*)d_in[3];
    const int*   dst_eids  = (const int*)d_in[4];
    const float* tarr      = (const float*)d_in[5];
    const float* W1        = (const float*)d_in[6];
    const float* b1        = (const float*)d_in[7];
    const float* Wfc       = (const float*)d_in[8];
    const float* bfc       = (const float*)d_in[9];
    float* out = (float*)d_out;

    const int B = in_sizes[3];
    const int grid = B / ROWS_PER_BLOCK;   // 262144 / 256 = 1024
    hipLaunchKernelGGL(tll_kernel, dim3(grid), dim3(256), 0, stream,
                       src_feat, dst_feat, timestamp, src_eids, dst_eids, tarr,
                       W1, b1, Wfc, bfc, out);
}